// Round 8
// baseline (555.658 us; speedup 1.0000x reference)
//
#include <hip/hip_runtime.h>
#include <math.h>

typedef _Float16 f16;
typedef _Float16 f16x8 __attribute__((ext_vector_type(8)));
typedef float f32x4 __attribute__((ext_vector_type(4)));

#define HH 32
#define WW 64
#define NPX 2048
#define SLOTS 68          // 64 px + 2 halo each side
#define CHS 78336         // 36*68*32 f16 = one 32-ci slab of the halo grid
// lo-planes pre-scaled by 2^11 to stay in fp16 NORMAL range (denormal inputs
// are flushed by the MFMA pipe -- proven by earlier bit-identical failure)
#define LOSCALE 2048.0f
#define INV_LOSCALE 4.8828125e-4f

typedef const __attribute__((address_space(1))) void gvoid;
typedef __attribute__((address_space(3))) void lvoid;
__device__ __forceinline__ void gload_lds16(const void* g, void* l) {
    __builtin_amdgcn_global_load_lds((gvoid*)g, (lvoid*)l, 16, 0, 0);
}

// ---- coalesced tiled repack (device fn, runs as a block role).
// Block = (coT: 16 co) x (cic: 32 ci) x all 25 taps. Bit-identical WP content.
__device__ __forceinline__ void repack_tile(
    const float* __restrict__ W, f16* __restrict__ WP, float* RAWF,
    int Cin, int nCoT, int nCic, int cpg_in_log2, int limb, int is_out,
    int coT, int cic, int plane)
{
    const int nt = blockDim.x, t = threadIdx.x;
    const int co0 = coT * 16, ci0 = cic * 32;
    for (int u = t; u < 3200; u += nt) {          // 12800 floats as float4
        int co16 = u / 200, j4 = u - co16 * 200;
        int co_p = co0 + co16;
        int co_orig = is_out ? 3 * (co_p >> 1) + 1 + (co_p & 1) : co_p;
        float4 v = *(const float4*)(W + (size_t)(co_orig * Cin + ci0) * 25 + j4 * 4);
        *(float4*)&RAWF[co16 * 800 + j4 * 4] = v;
    }
    __syncthreads();
    const int base = (coT * nCic + cic) * 512;
    const int tapStride = nCoT * nCic * 512;
    for (int e = t; e < 12800; e += nt) {
        int tap = e >> 9, r = e & 511;
        int co16 = r >> 5, ci32 = r & 31;
        int ky = tap / 5, kx = tap - 5 * ky;
        int co_p = co0 + co16;
        int g_out = is_out ? (co_p >> 1) : (co_p >> 2);
        int g_in = (ci0 + ci32) >> cpg_in_log2;
        float v = 0.f;
        if (ky + kx <= limb + g_out - g_in)
            v = RAWF[co16 * 800 + ci32 * 25 + tap];
        f16 vh = (f16)v;
        int dst = base + tap * tapStride + co16 * 32 + ci32;
        WP[dst] = vh;
        WP[plane + dst] = (f16)((v - (float)vh) * LOSCALE);
    }
}

// ---- init dispatch: role-split blocks. [0,1224): zero P|Q (int4);
// [1224,1836): prep X0 incl halo; [1836,1868): repack w_in -> WP.
__global__ __launch_bounds__(256) void init_kernel(
    const float* __restrict__ data, const float* __restrict__ mask,
    f16* __restrict__ PQ, f16* __restrict__ X0,
    const float* __restrict__ w_in, f16* __restrict__ WP)
{
    __shared__ __align__(16) float RAWF[12800];
    const int b = blockIdx.x, t = threadIdx.x;
    if (b < 1224) {
        *(int4*)(PQ + (size_t)(b * 256 + t) * 8) = make_int4(0, 0, 0, 0);
    } else if (b < 1836) {
        int e = (b - 1224) * 256 + t;          // [0, 156672): si*64 + ci
        int si = e >> 6, ci = e & 63;
        int row = si / 68, slot = si - row * 68;
        float v = 0.f;
        if (row >= 2 && row < 34 && slot >= 2 && slot < 66) {
            int px = (row - 2) * 64 + (slot - 2);
            v = (data[ci * NPX + px] - 3.5f) * mask[ci * NPX + px];
        }
        int dst = (ci >> 5) * CHS + si * 32 + (ci & 31);
        X0[dst] = (f16)v;
        X0[156672 + dst] = (f16)0.f;
    } else {
        int rb = b - 1836;
        repack_tile(w_in, WP, RAWF, 64, 16, 2, 0, 3, 0, rb >> 1, rb & 1, 409600);
    }
}

// ---- fused conv V9 = V7 (barrier-free per-wave staging, 424us best) +
// IN-WAVE SOFTWARE PIPELINE. Timeline model: 31us/conv = ~315 cyc per kx-iter
// per wave = ds-issue(32) + EXPOSED LDS latency(~100) + mfma-issue(58) +
// amortized exposed stage-drain(~100). Fixes:
//  (1) cross-kx register ping-pong (b0<->b1): kx+1's 8 ds_reads + A-frags
//      issue BEFORE kx's 12 MFMAs -> read batch covered by ~120cy of work.
//  (2) next-chunk stage (9 gloads) issues after lgkmcnt(0) but BEFORE the
//      last-kx MFMA cluster; chunk-top drain is counted vmcnt(2) (A-kx0 load
//      made unconditional so the count is exact; no vmcnt(0) in the loop).
//  (3) s_setprio(1) around MFMA clusters (waves desynced, role-diverse).
// MFMA order per (chunk,kx,j) bit-identical to V7.
#define LOADB(BH, BL, KX)                                   \
    BH##0 = *(const f16x8*)(bhp + (l15 + (KX)) * 32);       \
    BH##1 = *(const f16x8*)(bhp + (l15 + (KX) + 16) * 32);  \
    BH##2 = *(const f16x8*)(bhp + (l15 + (KX) + 32) * 32);  \
    BH##3 = *(const f16x8*)(bhp + (l15 + (KX) + 48) * 32);  \
    BL##0 = *(const f16x8*)(blp + (l15 + (KX)) * 32);       \
    BL##1 = *(const f16x8*)(blp + (l15 + (KX) + 16) * 32);  \
    BL##2 = *(const f16x8*)(blp + (l15 + (KX) + 32) * 32);  \
    BL##3 = *(const f16x8*)(blp + (l15 + (KX) + 48) * 32);

#define MFMA3(AH, AL, BH, BL, J)                                                    \
    acc_h[J] = __builtin_amdgcn_mfma_f32_16x16x32_f16(AH, BH, acc_h[J], 0, 0, 0);   \
    acc_m[J] = __builtin_amdgcn_mfma_f32_16x16x32_f16(AH, BL, acc_m[J], 0, 0, 0);   \
    acc_m[J] = __builtin_amdgcn_mfma_f32_16x16x32_f16(AL, BH, acc_m[J], 0, 0, 0);

#define MFMAS(AH, AL, BH, BL)            \
    __builtin_amdgcn_s_setprio(1);       \
    MFMA3(AH, AL, BH##0, BL##0, 0)       \
    MFMA3(AH, AL, BH##1, BL##1, 1)       \
    MFMA3(AH, AL, BH##2, BL##2, 2)       \
    MFMA3(AH, AL, BH##3, BL##3, 3)       \
    __builtin_amdgcn_s_setprio(0);

__global__ __launch_bounds__(320, 3) void conv_kernel(
    const f16* __restrict__ IN, int Cin, int inPlane,
    const f16* __restrict__ WP, int wPlane,
    const float* __restrict__ bias,
    const f16* __restrict__ RES, int resPlane,
    f16* __restrict__ OA, int oaPlane,
    float* __restrict__ OT,
    int nmt, int Coutp, int cpg_out, int cpg_in, int limb, int mode,
    const float* __restrict__ rW, f16* __restrict__ rWP,
    int rCin, int rnCoT, int rnCic, int rcpg_in_log2, int rlimb, int ris_out,
    int rplane, int nConv)
{
    __shared__ __align__(16) char SMEM[51200];   // conv: 46080; repack: 51200
    f16* BL = (f16*)SMEM;      // [wave5][pl0 row 4352B | pl1 row 4352B | pad 512]
    float* RED = (float*)SMEM; // [kw5][px64][co pad20] = 25600 B (after K loop)

    if (blockIdx.x >= (unsigned)nConv) {         // repack role (block-uniform)
        int rb = blockIdx.x - nConv;
        repack_tile(rW, rWP, (float*)SMEM, rCin, rnCoT, rnCic,
                    rcpg_in_log2, rlimb, ris_out, rb / rnCic, rb % rnCic, rplane);
        return;
    }

    const int t = threadIdx.x;
    const int kw = t >> 6;                 // wave index == ky
    const int lane = t & 63, l15 = lane & 15, q = lane >> 4;

    // XCD-affinity decode: pairIdx rides the low 3 bits (HW XCD round-robin).
    const int b = blockIdx.x;
    const int p3 = b & 7, r = b >> 3;
    int pairIdx, slot, h_;
    if (nmt == 16) { pairIdx = p3;     h_ = r & 31; slot = r >> 5; }
    else           { pairIdx = p3 & 3; h_ = r;      slot = p3 >> 2; }
    const int h = h_;
    const int mt = slot ? (nmt - 1 - pairIdx) : pairIdx;
    const int co0 = mt * 16;
    const int g_max = (co0 + 15) / cpg_out;

    // masked K-extent per kx for this wave's ky (allowed iff ky+kx<=limb+g_out-g_in)
    int cnt[5];
#pragma unroll
    for (int kx = 0; kx < 5; kx++) {
        int c = (g_max + limb - (kw + kx) + 1) * cpg_in;
        c = c < Cin ? c : Cin;
        cnt[kx] = c > 0 ? c : 0;
    }
    int ci_top = (g_max + limb + 1) * cpg_in;   // block-uniform chunk bound
    ci_top = ci_top < Cin ? ci_top : Cin;
    const int NT = (ci_top + 31) >> 5;

    // per-lane staging source offsets for THIS WAVE's rows (f16 units).
    int soff[9];
    const int rowg = (h + kw) * 2176;
#pragma unroll
    for (int r9 = 0; r9 < 9; ++r9) {
        int u = r9 * 64 + lane;
        if (u > 543) u = 543;
        int pl = u >= 272 ? 1 : 0;
        int rem = u - (pl ? 272 : 0);
        soff[r9] = pl * inPlane + rowg + rem * 8;
    }
    // wave-private LDS region: 576 16B-units = 4608 f16
    f16* const wreg = BL + kw * 4608;

    f32x4 acc_h[4], acc_m[4];
#pragma unroll
    for (int j = 0; j < 4; j++) {
        acc_h[j] = (f32x4){0.f, 0.f, 0.f, 0.f};
        acc_m[j] = (f32x4){0.f, 0.f, 0.f, 0.f};
    }

    // tiled weight addressing: tile (tap, mt, cic) is 512 f16 contiguous
    const size_t kxs = (size_t)Coutp * Cin;            // per-kx tap stride
    const f16* wb0 = WP + (size_t)(kw * 5 * (Coutp >> 4) + mt) * ((size_t)Cin << 4)
                   + l15 * 32 + q * 8;

    // prologue: stage chunk 0 (own rows only)
#pragma unroll
    for (int r9 = 0; r9 < 9; ++r9)
        gload_lds16(IN + soff[r9], wreg + r9 * 512);

    const f16* bhp = wreg + q * 8;          // [slot68][ci32], plane0
    const f16* blp = bhp + 2176;            // plane1

    for (int it = 0; it < NT; ++it) {
        const int ci0 = it << 5;
        const f16* wb = wb0 + it * 512;
        f16x8 a0h, a0l, a1h, a1l;
        f16x8 b0h0, b0h1, b0h2, b0h3, b0l0, b0l1, b0l2, b0l3;
        f16x8 b1h0, b1h1, b1h2, b1h3, b1l0, b1l1, b1l2, b1l3;

        // A kx0: UNCONDITIONAL (keeps vmcnt arithmetic exact; addr always valid)
        a0h = *(const f16x8*)(wb);
        a0l = *(const f16x8*)(wb + wPlane);
        // outstanding = 9 stage + 2 A -> wait until <=2: stage landed, A flying
        asm volatile("s_waitcnt vmcnt(2)" ::: "memory");

        if (ci0 < cnt[0]) { LOADB(b0h, b0l, 0) }            // kx0 B
        // ---- kx0: issue kx1, compute kx0
        if (ci0 < cnt[1]) {
            a1h = *(const f16x8*)(wb + kxs);
            a1l = *(const f16x8*)(wb + kxs + wPlane);
            LOADB(b1h, b1l, 1)
        }
        if (ci0 < cnt[0]) { MFMAS(a0h, a0l, b0h, b0l) }
        // ---- kx1: issue kx2, compute kx1
        if (ci0 < cnt[2]) {
            a0h = *(const f16x8*)(wb + 2 * kxs);
            a0l = *(const f16x8*)(wb + 2 * kxs + wPlane);
            LOADB(b0h, b0l, 2)
        }
        if (ci0 < cnt[1]) { MFMAS(a1h, a1l, b1h, b1l) }
        // ---- kx2: issue kx3, compute kx2
        if (ci0 < cnt[3]) {
            a1h = *(const f16x8*)(wb + 3 * kxs);
            a1l = *(const f16x8*)(wb + 3 * kxs + wPlane);
            LOADB(b1h, b1l, 3)
        }
        if (ci0 < cnt[2]) { MFMAS(a0h, a0l, b0h, b0l) }
        // ---- kx3: issue kx4, compute kx3
        if (ci0 < cnt[4]) {
            a0h = *(const f16x8*)(wb + 4 * kxs);
            a0l = *(const f16x8*)(wb + 4 * kxs + wPlane);
            LOADB(b0h, b0l, 4)
        }
        if (ci0 < cnt[3]) { MFMAS(a1h, a1l, b1h, b1l) }
        // ---- stage next chunk: all B reads landed -> safe to overwrite; its
        // latency is covered by kx4's MFMAs + next chunk's top overhead
        if (it + 1 < NT) {
            asm volatile("s_waitcnt lgkmcnt(0)" ::: "memory");
            const int coff = (it + 1) * CHS;
#pragma unroll
            for (int r9 = 0; r9 < 9; ++r9)
                gload_lds16(IN + soff[r9] + coff, wreg + r9 * 512);
        }
        // ---- kx4
        if (ci0 < cnt[4]) { MFMAS(a0h, a0l, b0h, b0l) }
    }

    // in-block ky reduction through LDS (C/D layout: px=j*16+l15, co=q*4+r)
    __syncthreads();   // drains ALL waves' loads/reads before RED aliases SMEM
#pragma unroll
    for (int j = 0; j < 4; j++) {
        f32x4 v;
#pragma unroll
        for (int rr = 0; rr < 4; rr++)
            v[rr] = acc_h[j][rr] + acc_m[j][rr] * INV_LOSCALE;
        *(f32x4*)&RED[(kw * 64 + j * 16 + l15) * 20 + q * 4] = v;
    }
    __syncthreads();

    if (mode == 0) {
        // bias + relu (+ residual) -> split-f16 halo store (chunk-major layout)
        for (int c = t; c < 1024; c += 320) {
            int px = c >> 4, col = c & 15;
            float v = bias[co0 + col];
#pragma unroll
            for (int k5 = 0; k5 < 5; k5++) v += RED[(k5 * 64 + px) * 20 + col];
            v = fmaxf(v, 0.f);
            int cc = co0 + col;
            int o = (cc >> 5) * CHS + ((h + 2) * SLOTS + px + 2) * 32 + (cc & 31);
            if (RES) v += (float)RES[o] + (float)RES[resPlane + o] * INV_LOSCALE;
            f16 vh = (f16)v;
            OA[o] = vh;
            OA[oaPlane + o] = (f16)((v - (float)vh) * LOSCALE);
        }
    } else {
        // output conv: co_p = g*2 + {mu,sig}; fold bias+softplus+erf table here
        for (int c = t; c < 1024; c += 320) {
            int px = c >> 4, col = c & 15;
            float v = bias[3 * ((co0 + col) >> 1) + 1 + (col & 1)];
#pragma unroll
            for (int k5 = 0; k5 < 5; k5++) v += RED[(k5 * 64 + px) * 20 + col];
            RED[px * 20 + col] = v;    // own-cell write after own-cell reads: safe
        }
        __syncthreads();
        for (int c = t; c < 512; c += 320) {
            int px = c >> 3, gl = c & 7;
            float mu = RED[px * 20 + 2 * gl];
            float s  = RED[px * 20 + 2 * gl + 1];
            float sp = fmaxf(s, 0.f) + log1pf(expf(-fabsf(s)));
            float sig = sp + 1e-6f;
            float inv = 1.f / (sig * 1.41421356237f);
            int g = (co0 >> 1) + gl;
            float* o = OT + ((size_t)g * NPX + h * WW + px) * 8;
#pragma unroll
            for (int k = 0; k < 8; k++) {
                float z = ((float)k - 3.0f - mu) * inv;
                o[k] = 32768.f * (1.f + erff(z));
            }
        }
    }
}

extern "C" void kernel_launch(void* const* d_in, const int* in_sizes, int n_in,
                              void* d_out, int out_size, void* d_ws, size_t ws_size,
                              hipStream_t stream) {
    const float* data  = (const float*)d_in[0];
    const float* mask  = (const float*)d_in[1];
    const float* w_in  = (const float*)d_in[2];
    const float* b_in  = (const float*)d_in[3];
    const float* w_hid = (const float*)d_in[4];
    const float* b_hid = (const float*)d_in[5];
    const float* w_out = (const float*)d_in[6];
    const float* b_out = (const float*)d_in[7];
    float* out = (float*)d_out;

    // ws: WPA 6.55MB | WPB 6.55 | P 2.51 | Q 2.51 | X0 0.63 = 18.75 MB
    f16* WPA = (f16*)d_ws;                 // ping-pong weight buffers
    f16* WPB = WPA + 3276800;
    f16* P   = WPB + 3276800;              // 2 x 8*CHS f16 (halo act, x)
    f16* Q   = P + 1253376;                // 2 x 8*CHS f16 (halo act, h1)
    f16* X0  = Q + 1253376;                // 2 x 2*CHS f16

    // init: zero P|Q (1224 blk) + prep X0 incl halo (612) + repack w_in (32)
    init_kernel<<<1868, 256, 0, stream>>>(data, mask, P, X0, w_in, WPA);

    f16* cur = WPA;
    f16* nxt = WPB;

    // c0: input conv X0->P (Cin=64, strict limb=3) + fused repack of w_hid[0]
    conv_kernel<<<640, 320, 0, stream>>>(X0, 64, 156672, cur, 409600,
        b_in, nullptr, 0, P, 626688, nullptr, 16, 256, 4, 1, 3, 0,
        w_hid, nxt, 256, 16, 8, 2, 4, 0, 1638400, 512);
    { f16* tmp = cur; cur = nxt; nxt = tmp; }

    // c1..c10: hidden convs; ck uses h_{k-1}, fused repack of h_k (k<10) or
    // w_out (k==10). odd k: P->Q; even k: Q->P with residual P.
    for (int k = 1; k <= 10; ++k) {
        const int isLast = (k == 10);
        const float* rw = isLast ? w_out : (w_hid + (size_t)k * 1638400);
        const int rgrid = isLast ? 64 : 128;
        const int rnCoT = isLast ? 8 : 16;
        const int ris   = isLast ? 1 : 0;
        const int rpl   = isLast ? 819200 : 1638400;
        if (k & 1)
            conv_kernel<<<512 + rgrid, 320, 0, stream>>>(P, 256, 626688, cur, 1638400,
                b_hid + (size_t)(k - 1) * 256, nullptr, 0, Q, 626688, nullptr,
                16, 256, 4, 4, 4, 0,
                rw, nxt, 256, rnCoT, 8, 2, 4, ris, rpl, 512);
        else
            conv_kernel<<<512 + rgrid, 320, 0, stream>>>(Q, 256, 626688, cur, 1638400,
                b_hid + (size_t)(k - 1) * 256, P, 626688, P, 626688, nullptr,
                16, 256, 4, 4, 4, 0,
                rw, nxt, 256, rnCoT, 8, 2, 4, ris, rpl, 512);
        f16* tmp = cur; cur = nxt; nxt = tmp;
    }

    // c11: output conv (mu/sig only, Coutp=128, cpg_out=2, limb=4) + erf table
    conv_kernel<<<256, 320, 0, stream>>>(P, 256, 626688, cur, 819200,
        b_out, nullptr, 0, nullptr, 0, out, 8, 128, 2, 4, 4, 1,
        nullptr, nullptr, 256, 8, 1, 2, 4, 0, 0, 256);
}

// Round 13
// 438.082 us; speedup vs baseline: 1.2684x; 1.2684x over previous
//
#include <hip/hip_runtime.h>
#include <math.h>

typedef _Float16 f16;
typedef _Float16 f16x4 __attribute__((ext_vector_type(4)));
typedef _Float16 f16x8 __attribute__((ext_vector_type(8)));
typedef float f32x4 __attribute__((ext_vector_type(4)));

#define HH 32
#define WW 64
#define NPX 2048
#define SLOTS 68          // 64 px + 2 halo each side
// ci row padded 32 -> 36 f16 (72B slot stride) to spread LDS banks.
// 72B is only 8B-aligned -> B fragments MUST be read as 2 x f16x4 (b64),
// never f16x8/b128 (V12 failed on misaligned ds_read_b128).
// Pad cells (ci 32..35 per slot) are staged into LDS but NEVER read by
// compute (q*8+7 <= 31) -> they need no initialization (V12/V13 zeroed them
// from a second block role -> intra-dispatch zero/prep race on X0 = the bug).
#define CIP 36
#define ROWF 2448         // 68*36 f16 per act row
#define CHS2 88128        // 36*68*36 f16 = one 32-ci slab (padded)
// lo-planes pre-scaled by 2^11 to stay in fp16 NORMAL range (denormal inputs
// are flushed by the MFMA pipe -- proven by earlier bit-identical failure)
#define LOSCALE 2048.0f
#define INV_LOSCALE 4.8828125e-4f

typedef const __attribute__((address_space(1))) void gvoid;
typedef __attribute__((address_space(3))) void lvoid;
__device__ __forceinline__ void gload_lds16(const void* g, void* l) {
    __builtin_amdgcn_global_load_lds((gvoid*)g, (lvoid*)l, 16, 0, 0);
}

// alignment-legal B load: two 8B-aligned f16x4 reads (ds_read_b64 pair)
__device__ __forceinline__ f16x8 ldB(const f16* p) {
    union { f16x4 h[2]; f16x8 v; } u;
    u.h[0] = *(const f16x4*)p;
    u.h[1] = *(const f16x4*)(p + 4);
    return u.v;
}

// ---- coalesced tiled repack (device fn, runs as a block role).
// Block = (coT: 16 co) x (cic: 32 ci) x all 25 taps. Bit-identical WP content.
__device__ __forceinline__ void repack_tile(
    const float* __restrict__ W, f16* __restrict__ WP, float* RAWF,
    int Cin, int nCoT, int nCic, int cpg_in_log2, int limb, int is_out,
    int coT, int cic, int plane)
{
    const int nt = blockDim.x, t = threadIdx.x;
    const int co0 = coT * 16, ci0 = cic * 32;
    for (int u = t; u < 3200; u += nt) {          // 12800 floats as float4
        int co16 = u / 200, j4 = u - co16 * 200;
        int co_p = co0 + co16;
        int co_orig = is_out ? 3 * (co_p >> 1) + 1 + (co_p & 1) : co_p;
        float4 v = *(const float4*)(W + (size_t)(co_orig * Cin + ci0) * 25 + j4 * 4);
        *(float4*)&RAWF[co16 * 800 + j4 * 4] = v;
    }
    __syncthreads();
    const int base = (coT * nCic + cic) * 512;
    const int tapStride = nCoT * nCic * 512;
    for (int e = t; e < 12800; e += nt) {
        int tap = e >> 9, r = e & 511;
        int co16 = r >> 5, ci32 = r & 31;
        int ky = tap / 5, kx = tap - 5 * ky;
        int co_p = co0 + co16;
        int g_out = is_out ? (co_p >> 1) : (co_p >> 2);
        int g_in = (ci0 + ci32) >> cpg_in_log2;
        float v = 0.f;
        if (ky + kx <= limb + g_out - g_in)
            v = RAWF[co16 * 800 + ci32 * 25 + tap];
        f16 vh = (f16)v;
        int dst = base + tap * tapStride + co16 * 32 + ci32;
        WP[dst] = vh;
        WP[plane + dst] = (f16)((v - (float)vh) * LOSCALE);
    }
}

// ---- init dispatch: role-split blocks, ranges DISJOINT (V12/V13 raced:
// zero role covered X0 while prep role wrote it -- blocks are unordered).
// [0,1377): zero P|Q real+pad (2,820,096 f16 exactly; halo cells ARE read as
// B operands so they must be zero). [1377,1989): prep X0 (interior + halo,
// both planes; pad cells unwritten -- never read by compute).
// [1989,2021): repack w_in -> WP.
__global__ __launch_bounds__(256) void init_kernel(
    const float* __restrict__ data, const float* __restrict__ mask,
    f16* __restrict__ PQ, f16* __restrict__ X0,
    const float* __restrict__ w_in, f16* __restrict__ WP)
{
    __shared__ __align__(16) float RAWF[12800];
    const int b = blockIdx.x, t = threadIdx.x;
    if (b < 1377) {
        *(int4*)(PQ + (size_t)(b * 256 + t) * 8) = make_int4(0, 0, 0, 0);
    } else if (b < 1989) {
        int e = (b - 1377) * 256 + t;      // [0, 156672): si*64 + ci
        int si = e >> 6, ci = e & 63;
        int row = si / 68, slot = si - row * 68;
        float v = 0.f;
        if (row >= 2 && row < 34 && slot >= 2 && slot < 66) {
            int px = (row - 2) * 64 + (slot - 2);
            v = (data[ci * NPX + px] - 3.5f) * mask[ci * NPX + px];
        }
        int dst = (ci >> 5) * CHS2 + si * CIP + (ci & 31);
        X0[dst] = (f16)v;
        X0[176256 + dst] = (f16)0.f;
    } else {
        int rb = b - 1989;
        repack_tile(w_in, WP, RAWF, 64, 16, 2, 0, 3, 0, rb >> 1, rb & 1, 409600);
    }
}

// ---- fused conv V14 = V13 conv, UNCHANGED (the V13 failure was the init
// race above, not this kernel). = V7 (barrier-free per-wave staging, proven
// 424.5us) + padded ci36 act layout + alignment-legal b64 B reads.
// Sync structure: per-wave stage (10 x 1KB gload_lds rounds into a private
// 10240B region), vmcnt(0) before compute, lgkmcnt(0) before next-chunk
// stage, no block barriers in the K loop. Numerics == V7.
__global__ __launch_bounds__(320, 3) void conv_kernel(
    const f16* __restrict__ IN, int Cin, int inPlane,
    const f16* __restrict__ WP, int wPlane,
    const float* __restrict__ bias,
    const f16* __restrict__ RES, int resPlane,
    f16* __restrict__ OA, int oaPlane,
    float* __restrict__ OT,
    int nmt, int Coutp, int cpg_out, int cpg_in, int limb, int mode,
    const float* __restrict__ rW, f16* __restrict__ rWP,
    int rCin, int rnCoT, int rnCic, int rcpg_in_log2, int rlimb, int ris_out,
    int rplane, int nConv)
{
    __shared__ __align__(16) char SMEM[51200];   // conv 51200; repack 51200
    f16* BLs = (f16*)SMEM;     // [wave5][5120 f16: pl0 row 2448 | pl1 2448 | pad]
    float* RED = (float*)SMEM; // [kw5][px64][co pad20] = 25600 B (after K loop)

    if (blockIdx.x >= (unsigned)nConv) {         // repack role (block-uniform)
        int rb = blockIdx.x - nConv;
        repack_tile(rW, rWP, (float*)SMEM, rCin, rnCoT, rnCic,
                    rcpg_in_log2, rlimb, ris_out, rb / rnCic, rb % rnCic, rplane);
        return;
    }

    const int t = threadIdx.x;
    const int kw = t >> 6;                 // wave index == ky
    const int lane = t & 63, l15 = lane & 15, q = lane >> 4;

    // XCD-affinity decode: pairIdx rides the low 3 bits (HW XCD round-robin).
    const int b = blockIdx.x;
    const int p3 = b & 7, r = b >> 3;
    int pairIdx, slot, h_;
    if (nmt == 16) { pairIdx = p3;     h_ = r & 31; slot = r >> 5; }
    else           { pairIdx = p3 & 3; h_ = r;      slot = p3 >> 2; }
    const int h = h_;
    const int mt = slot ? (nmt - 1 - pairIdx) : pairIdx;
    const int co0 = mt * 16;
    const int g_max = (co0 + 15) / cpg_out;

    // masked K-extent per kx for this wave's ky (allowed iff ky+kx<=limb+g_out-g_in)
    int cnt[5];
#pragma unroll
    for (int kx = 0; kx < 5; kx++) {
        int c = (g_max + limb - (kw + kx) + 1) * cpg_in;
        c = c < Cin ? c : Cin;
        cnt[kx] = c > 0 ? c : 0;
    }
    int ci_top = (g_max + limb + 1) * cpg_in;   // block-uniform chunk bound
    ci_top = ci_top < Cin ? ci_top : Cin;
    const int NT = (ci_top + 31) >> 5;

    // per-lane staging source offsets for THIS WAVE's rows (f16 units).
    // unit u in [0,612): pl = u>=306 (306 x 16B = 2448 f16 per plane-row).
    // 10 rounds x 64 lanes = 640 units; tail lanes clamped (dest = pad).
    int soff[10];
    const int rowg = (h + kw) * ROWF;
#pragma unroll
    for (int r10 = 0; r10 < 10; ++r10) {
        int u = r10 * 64 + lane;
        if (u > 611) u = 611;
        int pl = u >= 306 ? 1 : 0;
        int rem = u - (pl ? 306 : 0);
        soff[r10] = pl * inPlane + rowg + rem * 8;
    }
    // wave-private LDS region: 640 16B-units = 5120 f16
    f16* const wreg = BLs + kw * 5120;

    f32x4 acc_h[4], acc_m[4];
#pragma unroll
    for (int j = 0; j < 4; j++) {
        acc_h[j] = (f32x4){0.f, 0.f, 0.f, 0.f};
        acc_m[j] = (f32x4){0.f, 0.f, 0.f, 0.f};
    }

    // tiled weight addressing: tile (tap, mt, cic) is 512 f16 contiguous
    const size_t kxs = (size_t)Coutp * Cin;            // per-kx tap stride
    const f16* wb0 = WP + (size_t)(kw * 5 * (Coutp >> 4) + mt) * ((size_t)Cin << 4)
                   + l15 * 32 + q * 8;

    // prologue: stage chunk 0 (own rows only)
#pragma unroll
    for (int r10 = 0; r10 < 10; ++r10)
        gload_lds16(IN + soff[r10], wreg + r10 * 512);

    for (int it = 0; it < NT; ++it) {
        const int ci0 = it << 5;
        // kx=0 A-frags issued BEFORE the wait: latency overlaps the stage drain
        const f16* wb = wb0 + it * 512;
        f16x8 cah, cal, nah, nal;
        if (ci0 < cnt[0]) {
            cah = *(const f16x8*)(wb);
            cal = *(const f16x8*)(wb + wPlane);
        }
        asm volatile("s_waitcnt vmcnt(0)" ::: "memory");   // own stage landed

        const f16* bhp = wreg + q * 8;          // [slot68][ci36], plane0
        const f16* blp = bhp + ROWF;            // plane1
#pragma unroll
        for (int kx = 0; kx < 5; kx++) {
            if (ci0 >= cnt[kx]) break;          // per-wave: barrier-free
            if (kx < 4 && ci0 < cnt[kx + 1]) {
                nah = *(const f16x8*)(wb + (kx + 1) * kxs);
                nal = *(const f16x8*)(wb + (kx + 1) * kxs + wPlane);
            }
            f16x8 bh[4], bl[4];
#pragma unroll
            for (int j = 0; j < 4; j++) {
                int slt = j * 16 + l15 + kx;
                bh[j] = ldB(bhp + slt * CIP);
                bl[j] = ldB(blp + slt * CIP);
            }
#pragma unroll
            for (int j = 0; j < 4; j++) {
                acc_h[j] = __builtin_amdgcn_mfma_f32_16x16x32_f16(cah, bh[j], acc_h[j], 0, 0, 0);
                acc_m[j] = __builtin_amdgcn_mfma_f32_16x16x32_f16(cah, bl[j], acc_m[j], 0, 0, 0);
                acc_m[j] = __builtin_amdgcn_mfma_f32_16x16x32_f16(cal, bh[j], acc_m[j], 0, 0, 0);
            }
            cah = nah; cal = nal;
        }
        if (it + 1 < NT) {
            // own ds_reads complete (MFMAs forced them) -> safe to overwrite
            asm volatile("s_waitcnt lgkmcnt(0)" ::: "memory");
            const int coff = (it + 1) * CHS2;
#pragma unroll
            for (int r10 = 0; r10 < 10; ++r10)
                gload_lds16(IN + soff[r10] + coff, wreg + r10 * 512);
        }
    }

    // in-block ky reduction through LDS (C/D layout: px=j*16+l15, co=q*4+r)
    __syncthreads();   // drains ALL waves' loads/reads before RED aliases SMEM
#pragma unroll
    for (int j = 0; j < 4; j++) {
        f32x4 v;
#pragma unroll
        for (int rr = 0; rr < 4; rr++)
            v[rr] = acc_h[j][rr] + acc_m[j][rr] * INV_LOSCALE;
        *(f32x4*)&RED[(kw * 64 + j * 16 + l15) * 20 + q * 4] = v;
    }
    __syncthreads();

    if (mode == 0) {
        // bias + relu (+ residual) -> split-f16 halo store (padded layout)
        for (int c = t; c < 1024; c += 320) {
            int px = c >> 4, col = c & 15;
            float v = bias[co0 + col];
#pragma unroll
            for (int k5 = 0; k5 < 5; k5++) v += RED[(k5 * 64 + px) * 20 + col];
            v = fmaxf(v, 0.f);
            int cc = co0 + col;
            int o = (cc >> 5) * CHS2 + ((h + 2) * SLOTS + px + 2) * CIP + (cc & 31);
            if (RES) v += (float)RES[o] + (float)RES[resPlane + o] * INV_LOSCALE;
            f16 vh = (f16)v;
            OA[o] = vh;
            OA[oaPlane + o] = (f16)((v - (float)vh) * LOSCALE);
        }
    } else {
        // output conv: co_p = g*2 + {mu,sig}; fold bias+softplus+erf table here
        for (int c = t; c < 1024; c += 320) {
            int px = c >> 4, col = c & 15;
            float v = bias[3 * ((co0 + col) >> 1) + 1 + (col & 1)];
#pragma unroll
            for (int k5 = 0; k5 < 5; k5++) v += RED[(k5 * 64 + px) * 20 + col];
            RED[px * 20 + col] = v;    // own-cell write after own-cell reads: safe
        }
        __syncthreads();
        for (int c = t; c < 512; c += 320) {
            int px = c >> 3, gl = c & 7;
            float mu = RED[px * 20 + 2 * gl];
            float s  = RED[px * 20 + 2 * gl + 1];
            float sp = fmaxf(s, 0.f) + log1pf(expf(-fabsf(s)));
            float sig = sp + 1e-6f;
            float inv = 1.f / (sig * 1.41421356237f);
            int g = (co0 >> 1) + gl;
            float* o = OT + ((size_t)g * NPX + h * WW + px) * 8;
#pragma unroll
            for (int k = 0; k < 8; k++) {
                float z = ((float)k - 3.0f - mu) * inv;
                o[k] = 32768.f * (1.f + erff(z));
            }
        }
    }
}

extern "C" void kernel_launch(void* const* d_in, const int* in_sizes, int n_in,
                              void* d_out, int out_size, void* d_ws, size_t ws_size,
                              hipStream_t stream) {
    const float* data  = (const float*)d_in[0];
    const float* mask  = (const float*)d_in[1];
    const float* w_in  = (const float*)d_in[2];
    const float* b_in  = (const float*)d_in[3];
    const float* w_hid = (const float*)d_in[4];
    const float* b_hid = (const float*)d_in[5];
    const float* w_out = (const float*)d_in[6];
    const float* b_out = (const float*)d_in[7];
    float* out = (float*)d_out;

    // ws: WPA 6.55MB | WPB 6.55 | P 2.82 | Q 2.82 | X0 0.71 = 19.5 MB
    f16* WPA = (f16*)d_ws;                 // ping-pong weight buffers
    f16* WPB = WPA + 3276800;
    f16* P   = WPB + 3276800;              // 2 x 8*CHS2 f16 (halo act, x)
    f16* Q   = P + 1410048;                // 2 x 8*CHS2 f16 (halo act, h1)
    f16* X0  = Q + 1410048;                // 2 x 2*CHS2 f16

    // init: zero P|Q (1377 blk, disjoint) + prep X0 (612) + repack w_in (32)
    init_kernel<<<2021, 256, 0, stream>>>(data, mask, P, X0, w_in, WPA);

    f16* cur = WPA;
    f16* nxt = WPB;

    // c0: input conv X0->P (Cin=64, strict limb=3) + fused repack of w_hid[0]
    conv_kernel<<<640, 320, 0, stream>>>(X0, 64, 176256, cur, 409600,
        b_in, nullptr, 0, P, 705024, nullptr, 16, 256, 4, 1, 3, 0,
        w_hid, nxt, 256, 16, 8, 2, 4, 0, 1638400, 512);
    { f16* tmp = cur; cur = nxt; nxt = tmp; }

    // c1..c10: hidden convs; ck uses h_{k-1}, fused repack of h_k (k<10) or
    // w_out (k==10). odd k: P->Q; even k: Q->P with residual P.
    for (int k = 1; k <= 10; ++k) {
        const int isLast = (k == 10);
        const float* rw = isLast ? w_out : (w_hid + (size_t)k * 1638400);
        const int rgrid = isLast ? 64 : 128;
        const int rnCoT = isLast ? 8 : 16;
        const int ris   = isLast ? 1 : 0;
        const int rpl   = isLast ? 819200 : 1638400;
        if (k & 1)
            conv_kernel<<<512 + rgrid, 320, 0, stream>>>(P, 256, 705024, cur, 1638400,
                b_hid + (size_t)(k - 1) * 256, nullptr, 0, Q, 705024, nullptr,
                16, 256, 4, 4, 4, 0,
                rw, nxt, 256, rnCoT, 8, 2, 4, ris, rpl, 512);
        else
            conv_kernel<<<512 + rgrid, 320, 0, stream>>>(Q, 256, 705024, cur, 1638400,
                b_hid + (size_t)(k - 1) * 256, P, 705024, P, 705024, nullptr,
                16, 256, 4, 4, 4, 0,
                rw, nxt, 256, rnCoT, 8, 2, 4, ris, rpl, 512);
        f16* tmp = cur; cur = nxt; nxt = tmp;
    }

    // c11: output conv (mu/sig only, Coutp=128, cpg_out=2, limb=4) + erf table
    conv_kernel<<<256, 320, 0, stream>>>(P, 256, 705024, cur, 819200,
        b_out, nullptr, 0, nullptr, 0, out, 8, 128, 2, 4, 4, 1,
        nullptr, nullptr, 256, 8, 1, 2, 4, 0, 0, 256);
}